// Round 6
// baseline (245.879 us; speedup 1.0000x reference)
//
#include <hip/hip_runtime.h>
#include <cstdint>
#include <cstddef>

typedef float f32x4 __attribute__((ext_vector_type(4)));
typedef short s16x8 __attribute__((ext_vector_type(8)));
typedef short s16x4 __attribute__((ext_vector_type(4)));

#define MFMA_BF16(a, b, c) __builtin_amdgcn_mfma_f32_16x16x32_bf16((a), (b), (c), 0, 0, 0)

// async global->LDS DMA, 16B/lane: lands at ldsbase + lane*16 (wave-uniform base)
#define GLD16(g, l)                                                            \
  __builtin_amdgcn_global_load_lds(                                            \
      (const __attribute__((address_space(1))) void*)(g),                      \
      (__attribute__((address_space(3))) void*)(l), 16, 0, 0)

__device__ __forceinline__ unsigned short f2bf(float f) {
  unsigned int u = __float_as_uint(f);
  u += 0x7FFFu + ((u >> 16) & 1u);
  return (unsigned short)(u >> 16);
}

__device__ __forceinline__ s16x8 cvt8(const float* __restrict__ src) {
  const float4 f0 = *(const float4*)src;
  const float4 f1 = *(const float4*)(src + 4);
  s16x8 h;
  h[0] = (short)f2bf(f0.x); h[1] = (short)f2bf(f0.y);
  h[2] = (short)f2bf(f0.z); h[3] = (short)f2bf(f0.w);
  h[4] = (short)f2bf(f1.x); h[5] = (short)f2bf(f1.y);
  h[6] = (short)f2bf(f1.z); h[7] = (short)f2bf(f1.w);
  return h;
}

__device__ __forceinline__ s16x8 cvt8r(float4 f0, float4 f1) {
  s16x8 h;
  h[0] = (short)f2bf(f0.x); h[1] = (short)f2bf(f0.y);
  h[2] = (short)f2bf(f0.z); h[3] = (short)f2bf(f0.w);
  h[4] = (short)f2bf(f1.x); h[5] = (short)f2bf(f1.y);
  h[6] = (short)f2bf(f1.z); h[7] = (short)f2bf(f1.w);
  return h;
}

// ---------------------------------------------------------------------------
// cvt_w: weights only (w_qkv[0:1024] -> wb, w_out -> wob). x conversion is
// now fused into gemm_qk (saves the 96MB x round-trip + a big dispatch).
// ---------------------------------------------------------------------------
#define WQN 524288    // 1024*512
__global__ __launch_bounds__(256)
void cvt_w(const float* __restrict__ wqkv, const float* __restrict__ wout,
           unsigned short* __restrict__ wb, unsigned short* __restrict__ wob) {
  const size_t i = (size_t)(blockIdx.x * 256 + threadIdx.x) * 8;
  const float* src;
  unsigned short* dst;
  if (i < WQN) { src = wqkv + i; dst = wb + i; }
  else { src = wout + (i - WQN); dst = wob + (i - WQN); }
  *(s16x8*)dst = cvt8(src);
}

// ---------------------------------------------------------------------------
// gemm_qk: [Q|K] = x @ wb^T with FUSED f32->bf16 of x. M=32768 N=1024 K=512.
// A (=W tile, As) stays GLD16 from bf16 wb. B (=x tile, Bs) is reg-staged:
// 8 dwordx4 f32 loads for chunk kc+1 issued before the barrier (T14), then
// f2bf+ds_write_b128 reproducing GLD16's landing pattern exactly:
//   row = wid*32+ii*8+(lane>>3), LDS col-block = lane&7, src col-block =
//   (lane&7)^(lane>>3)  -> read-side XOR swizzle unchanged, bit-identical.
// Counted vmcnt(8) keeps x(kc+1) in flight across the barrier.
// ---------------------------------------------------------------------------
__global__ __launch_bounds__(256)
void gemm_qk(const float* __restrict__ x, const unsigned short* __restrict__ wb,
             unsigned short* __restrict__ Q, unsigned short* __restrict__ K) {
  __shared__ unsigned short As[128 * 64];  // W tile
  __shared__ unsigned short Bs[128 * 64];  // x tile (converted in-kernel)
  const int t = threadIdx.x, lane = t & 63, wid = t >> 6;
  const int wm = wid >> 1, wn = wid & 1;
  const int nl = lane & 15, quad = lane >> 4;
  const int sub = lane >> 3, lblk = (lane & 7) ^ sub;
  const int l = blockIdx.x;
  const int xcd = l & 7, g = l >> 3;
  const int mt = (g >> 3) * 8 + xcd, nt = g & 7;
  const int m0 = mt * 128, n0 = nt * 128;

  const f32x4 zero = {0.f, 0.f, 0.f, 0.f};
  f32x4 acc[4][4];
#pragma unroll
  for (int i = 0; i < 4; ++i)
#pragma unroll
    for (int j = 0; j < 4; ++j) acc[i][j] = zero;

  const float* gXf = x + (size_t)(m0 + wid * 32 + sub) * 512 + lblk * 8;
  const unsigned short* gW = wb + (size_t)(n0 + wid * 32 + sub) * 512 + lblk * 8;

  float4 rx[4][2];  // chunk staging regs: 4 rows/wavelane-group x 8 f32
#define LOADX(kcc)                                                             \
  do {                                                                         \
    _Pragma("unroll") for (int ii = 0; ii < 4; ++ii) {                         \
      const float* p_ = gXf + (kcc) + ii * 4096; /* 8 rows * 512 */            \
      rx[ii][0] = *(const float4*)p_;                                          \
      rx[ii][1] = *(const float4*)(p_ + 4);                                    \
    }                                                                          \
  } while (0)

  LOADX(0);
  for (int kc = 0; kc < 512; kc += 64) {
#pragma unroll
    for (int ii = 0; ii < 4; ++ii)
      GLD16(gW + kc + (size_t)(ii * 8) * 512, &As[(wid * 32 + ii * 8) * 64]);
    // convert current chunk's regs -> Bs (compiler auto-waits vmcnt for rx,
    // leaving the newer As GLD16s in flight)
#pragma unroll
    for (int ii = 0; ii < 4; ++ii)
      *(s16x8*)&Bs[(wid * 32 + ii * 8 + sub) * 64 + (lane & 7) * 8] =
          cvt8r(rx[ii][0], rx[ii][1]);
    if (kc < 448) {
      LOADX(kc + 64);  // next chunk flies under this chunk's MFMA
      asm volatile("s_waitcnt vmcnt(8) lgkmcnt(0)" ::: "memory");  // As done
    } else {
      asm volatile("s_waitcnt vmcnt(0) lgkmcnt(0)" ::: "memory");
    }
    __builtin_amdgcn_s_barrier();
    asm volatile("" ::: "memory");
#pragma unroll
    for (int ks = 0; ks < 2; ++ks) {
      s16x8 af[4], bf[4];
#pragma unroll
      for (int i = 0; i < 4; ++i)
        af[i] = *(const s16x8*)&As[(wm * 64 + i * 16 + nl) * 64 +
                                   (((ks * 4 + quad) ^ (nl & 7)) * 8)];
#pragma unroll
      for (int j = 0; j < 4; ++j)
        bf[j] = *(const s16x8*)&Bs[(wn * 64 + j * 16 + nl) * 64 +
                                   (((ks * 4 + quad) ^ (nl & 7)) * 8)];
      __builtin_amdgcn_s_setprio(1);
#pragma unroll
      for (int i = 0; i < 4; ++i)
#pragma unroll
        for (int j = 0; j < 4; ++j) acc[i][j] = MFMA_BF16(af[i], bf[j], acc[i][j]);
      __builtin_amdgcn_s_setprio(0);
    }
    asm volatile("" ::: "memory");
    __builtin_amdgcn_s_barrier();
  }
#undef LOADX
#pragma unroll
  for (int i = 0; i < 4; ++i) {
    const int n = n0 + wm * 64 + i * 16 + quad * 4;
    unsigned short* base = (n < 512 ? Q : K);
    const int nn = n & 511;
#pragma unroll
    for (int j = 0; j < 4; ++j) {
      const int m = m0 + wn * 64 + j * 16 + nl;
      s16x4 h;
#pragma unroll
      for (int r = 0; r < 4; ++r) h[r] = (short)f2bf(acc[i][j][r]);
      *(s16x4*)&base[(size_t)m * 512 + nn] = h;
    }
  }
}

// ---------------------------------------------------------------------------
// gemm_kwt: KWT[b][o][seq] = (K @ wob^T)^T — output projection hoisted before
// attention. Normal operand order -> packed 8B transposed stores. (unchanged)
// ---------------------------------------------------------------------------
__global__ __launch_bounds__(256)
void gemm_kwt(const unsigned short* __restrict__ K, const unsigned short* __restrict__ wob,
              unsigned short* __restrict__ KWT) {
  __shared__ unsigned short As[128 * 64];
  __shared__ unsigned short Bs[128 * 64];
  const int t = threadIdx.x, lane = t & 63, wid = t >> 6;
  const int wm = wid >> 1, wn = wid & 1;
  const int nl = lane & 15, quad = lane >> 4;
  const int sub = lane >> 3, lblk = (lane & 7) ^ sub;
  const int l = blockIdx.x;
  const int xcd = l & 7, g = l >> 3;
  const int mt = (g >> 2) * 8 + xcd, nt = g & 3;
  const int m0 = mt * 128, n0 = nt * 128;

  const f32x4 zero = {0.f, 0.f, 0.f, 0.f};
  f32x4 acc[4][4];
#pragma unroll
  for (int i = 0; i < 4; ++i)
#pragma unroll
    for (int j = 0; j < 4; ++j) acc[i][j] = zero;

  const unsigned short* gA = K + (size_t)(m0 + wid * 32 + sub) * 512 + lblk * 8;
  const unsigned short* gB = wob + (size_t)(n0 + wid * 32 + sub) * 512 + lblk * 8;

  for (int kc = 0; kc < 512; kc += 64) {
#pragma unroll
    for (int ii = 0; ii < 4; ++ii) {
      GLD16(gA + kc + (size_t)(ii * 8) * 512, &As[(wid * 32 + ii * 8) * 64]);
      GLD16(gB + kc + (size_t)(ii * 8) * 512, &Bs[(wid * 32 + ii * 8) * 64]);
    }
    __syncthreads();
#pragma unroll
    for (int ks = 0; ks < 2; ++ks) {
      s16x8 af[4], bf[4];
#pragma unroll
      for (int i = 0; i < 4; ++i)
        af[i] = *(const s16x8*)&As[(wm * 64 + i * 16 + nl) * 64 +
                                   (((ks * 4 + quad) ^ (nl & 7)) * 8)];
#pragma unroll
      for (int j = 0; j < 4; ++j)
        bf[j] = *(const s16x8*)&Bs[(wn * 64 + j * 16 + nl) * 64 +
                                   (((ks * 4 + quad) ^ (nl & 7)) * 8)];
#pragma unroll
      for (int i = 0; i < 4; ++i)
#pragma unroll
        for (int j = 0; j < 4; ++j) acc[i][j] = MFMA_BF16(af[i], bf[j], acc[i][j]);
    }
    __syncthreads();
  }
#pragma unroll
  for (int i = 0; i < 4; ++i) {
    const int ms = m0 + wm * 64 + i * 16 + quad * 4;
    const int b = ms >> 13, ns = ms & 8191;
#pragma unroll
    for (int j = 0; j < 4; ++j) {
      const int o = n0 + wn * 64 + j * 16 + nl;
      s16x4 h;
#pragma unroll
      for (int r = 0; r < 4; ++r) h[r] = (short)f2bf(acc[i][j][r]);
      *(s16x4*)&KWT[(size_t)(b * 512 + o) * 8192 + ns] = h;
    }
  }
}

// ---------------------------------------------------------------------------
// attn64 v6 (R5 verbatim — best measured at 56.6us): K dbuf + single-Q
// counted-vmcnt pipeline, 72KB LDS, phase 2 dbuf counted-vmcnt with barriers.
// ---------------------------------------------------------------------------
__global__ __launch_bounds__(256)
void attn64(const unsigned short* __restrict__ Q, const unsigned short* __restrict__ K,
            const unsigned short* __restrict__ KWT, const float* __restrict__ bias,
            float* __restrict__ out) {
  __shared__ __align__(16) char smem[73728];
  unsigned short* const Qb  = (unsigned short*)smem;             // 8KB  [0,8K)
  unsigned short* const Kbo = (unsigned short*)(smem + 8192);    // 32KB [8K,40K)  odd chunks
  unsigned short* const Kbe = (unsigned short*)(smem + 40960);   // 32KB [40K,72K) even chunks
  unsigned short* const Ps  = (unsigned short*)smem;             // 32KB [0,32K)   phase2
  float* const redm = (float*)(smem + 32768);                    // 1KB (dead Kbo top)
  float* const reds = (float*)(smem + 33792);                    // 1KB
  unsigned short* const B20 = (unsigned short*)(smem + 40960);   // 16KB alias Kbe
  unsigned short* const B21 = (unsigned short*)(smem + 57344);   // 16KB alias Kbe

  const int t = threadIdx.x, lane = t & 63, wid = t >> 6;
  const int wn = wid;  // 4 waves split the 256 sim cols
  const int nl = lane & 15, quad = lane >> 4;
  const int sub = lane >> 3, lblk = (lane & 7) ^ sub;
  // paired-XCD decode: bx = g*16 + half*8 + xcd
  const int bx = blockIdx.x;
  const int xcd = bx & 7, half = (bx >> 3) & 1, g = bx >> 4;
  const int wb = g * 8 + xcd, b = wb >> 6, w = wb & 63;

  const unsigned short* Qg = Q + (size_t)(b * 8192 + w * 128 + half * 64) * 512;
  const unsigned short* Kg = K + (size_t)(b * 8192) * 512;
  const unsigned short* KWTb = KWT + (size_t)(b * 512) * 8192;
  const int seqbase = w * 128 - 128;

#define STAGE_Q(kcc)                                                           \
  do {                                                                         \
    _Pragma("unroll") for (int ii = 0; ii < 2; ++ii)                           \
        GLD16(Qg + (size_t)(wid * 16 + ii * 8 + sub) * 512 + (kcc) + lblk * 8, \
              Qb + (wid * 16 + ii * 8) * 64);                                  \
  } while (0)

#define STAGE_K(kcc, kb)                                                       \
  do {                                                                         \
    _Pragma("unroll") for (int ii = 0; ii < 8; ++ii) {                         \
      int sq_ = seqbase + wid * 64 + ii * 8 + sub;                             \
      if (sq_ < 0) sq_ = 0;                                                    \
      GLD16(Kg + (size_t)sq_ * 512 + (kcc) + lblk * 8,                         \
            (kb) + (wid * 64 + ii * 8) * 64);                                  \
    }                                                                          \
  } while (0)

#define STAGE_B2(tt, bb)                                                       \
  do {                                                                         \
    const int och_ = (tt) >> 2, kch_ = (tt) & 3;                               \
    int sq_ = seqbase + kch_ * 64 + lblk * 8;                                  \
    if (sq_ < 0) sq_ = 0;                                                      \
    _Pragma("unroll") for (int ii = 0; ii < 4; ++ii)                           \
        GLD16(KWTb + (size_t)(och_ * 128 + wid * 32 + ii * 8 + sub) * 8192 + sq_, \
              (bb) + (wid * 32 + ii * 8) * 64);                                \
  } while (0)

  float bo[4][2];
#pragma unroll
  for (int och = 0; och < 4; ++och)
#pragma unroll
    for (int j = 0; j < 2; ++j) bo[och][j] = bias[och * 128 + wn * 32 + j * 16 + nl];

  const f32x4 zero = {0.f, 0.f, 0.f, 0.f};
  f32x4 acc[4][4];
#pragma unroll
  for (int i = 0; i < 4; ++i)
#pragma unroll
    for (int j = 0; j < 4; ++j) acc[i][j] = zero;

  // ---- phase 1: sim = Q.K2^T, K dbuf + single-Q counted-vmcnt pipeline ----
  STAGE_K(0, Kbe);
  STAGE_Q(0);
#pragma unroll
  for (int s = 0; s < 8; ++s) {
    unsigned short* const kb = (s & 1) ? Kbo : Kbe;
    if (s < 7) {
      STAGE_K((s + 1) * 64, (s & 1) ? Kbe : Kbo);
      asm volatile("s_waitcnt vmcnt(8)" ::: "memory");  // K(s),Q(s) ready; K(s+1) in flight
    } else {
      STAGE_B2(0, B20);  // Kbe dead after s=6 -> phase-2 prefetch begins
      asm volatile("s_waitcnt vmcnt(4)" ::: "memory");
    }
    __builtin_amdgcn_s_barrier();
    asm volatile("" ::: "memory");
#pragma unroll
    for (int ks = 0; ks < 2; ++ks) {
      s16x8 af[4], bf[4];
#pragma unroll
      for (int i = 0; i < 4; ++i)
        af[i] = *(const s16x8*)&Qb[(i * 16 + nl) * 64 +
                                   (((ks * 4 + quad) ^ (nl & 7)) * 8)];
#pragma unroll
      for (int j = 0; j < 4; ++j)
        bf[j] = *(const s16x8*)&kb[(wn * 64 + j * 16 + nl) * 64 +
                                   (((ks * 4 + quad) ^ (nl & 7)) * 8)];
      __builtin_amdgcn_s_setprio(1);
#pragma unroll
      for (int i = 0; i < 4; ++i)
#pragma unroll
        for (int j = 0; j < 4; ++j) acc[i][j] = MFMA_BF16(af[i], bf[j], acc[i][j]);
      __builtin_amdgcn_s_setprio(0);
    }
    asm volatile("" ::: "memory");
    __builtin_amdgcn_s_barrier();
    if (s < 7) STAGE_Q((s + 1) * 64);  // Qb reads of step s done (barrier above)
  }
  STAGE_B2(1, B21);  // second phase-2 chunk rides under softmax

  // ---- softmax (raw barriers; no vmcnt drains) ----
  const float scale = 0.04419417382415922f;  // 512^-0.5
  float rmax[4][4];
#pragma unroll
  for (int i = 0; i < 4; ++i) {
#pragma unroll
    for (int r = 0; r < 4; ++r) {
      const int qrow = half * 64 + i * 16 + quad * 4 + r;  // within-window row
      float mx = -3.4e38f;
#pragma unroll
      for (int j = 0; j < 4; ++j) {
        const int col = wn * 64 + j * 16 + nl;
        float v = acc[i][j][r] * scale;
        if (col >= 128 && col - 128 > qrow) v = -3.0e38f;  // causal mask
        if (w == 0 && col < 128) v = 0.0f;                 // zero bucket: sim=0
        acc[i][j][r] = v;
        mx = fmaxf(mx, v);
      }
      rmax[i][r] = mx;
    }
  }
#pragma unroll
  for (int off = 1; off < 16; off <<= 1)
#pragma unroll
    for (int i = 0; i < 4; ++i)
#pragma unroll
      for (int r = 0; r < 4; ++r)
        rmax[i][r] = fmaxf(rmax[i][r], __shfl_xor(rmax[i][r], off, 64));
  if (nl == 0) {
#pragma unroll
    for (int i = 0; i < 4; ++i)
#pragma unroll
      for (int r = 0; r < 4; ++r)
        redm[(i * 16 + quad * 4 + r) * 4 + wn] = rmax[i][r];
  }
  asm volatile("s_waitcnt lgkmcnt(0)" ::: "memory");
  __builtin_amdgcn_s_barrier();
  asm volatile("" ::: "memory");
  float rsum[4][4];
#pragma unroll
  for (int i = 0; i < 4; ++i) {
#pragma unroll
    for (int r = 0; r < 4; ++r) {
      const f32x4 mv = *(const f32x4*)&redm[(i * 16 + quad * 4 + r) * 4];
      const float m = fmaxf(fmaxf(mv[0], mv[1]), fmaxf(mv[2], mv[3]));
      float s = 0.f;
#pragma unroll
      for (int j = 0; j < 4; ++j) {
        const float p = __expf(acc[i][j][r] - m);
        acc[i][j][r] = p;
        s += p;
      }
      rsum[i][r] = s;
    }
  }
#pragma unroll
  for (int off = 1; off < 16; off <<= 1)
#pragma unroll
    for (int i = 0; i < 4; ++i)
#pragma unroll
      for (int r = 0; r < 4; ++r) rsum[i][r] += __shfl_xor(rsum[i][r], off, 64);
  if (nl == 0) {
#pragma unroll
    for (int i = 0; i < 4; ++i)
#pragma unroll
      for (int r = 0; r < 4; ++r)
        reds[(i * 16 + quad * 4 + r) * 4 + wn] = rsum[i][r];
  }
  asm volatile("s_waitcnt lgkmcnt(0)" ::: "memory");
  __builtin_amdgcn_s_barrier();
  asm volatile("" ::: "memory");
  float invv[4][4];
#pragma unroll
  for (int i = 0; i < 4; ++i)
#pragma unroll
    for (int r = 0; r < 4; ++r) {
      const f32x4 sv = *(const f32x4*)&reds[(i * 16 + quad * 4 + r) * 4];
      invv[i][r] = 1.0f / (sv[0] + sv[1] + sv[2] + sv[3]);
    }
  asm volatile("s_waitcnt lgkmcnt(0)" ::: "memory");
  __builtin_amdgcn_s_barrier();
  asm volatile("" ::: "memory");
  // normalize, write P -> LDS (swizzled row-major 64x256 bf16)
#pragma unroll
  for (int i = 0; i < 4; ++i) {
#pragma unroll
    for (int r = 0; r < 4; ++r) {
      const int row = i * 16 + quad * 4 + r;
#pragma unroll
      for (int j = 0; j < 4; ++j) {
        const int col = wn * 64 + j * 16 + nl;
        float pv = acc[i][j][r] * invv[i][r];
        if (w == 0 && col < 128) pv = 0.0f;  // zero V bucket
        const int cb = col >> 3;
        Ps[row * 256 + (((cb ^ (row & 7)) << 3) | (col & 7))] = f2bf(pv);
      }
    }
  }
  asm volatile("s_waitcnt lgkmcnt(0)" ::: "memory");
  __builtin_amdgcn_s_barrier();
  asm volatile("" ::: "memory");

  // ---- phase 2: out = P @ KWT^T, dbuf counted-vmcnt ----
  f32x4 acc2[4][2];
#pragma unroll
  for (int t2 = 0; t2 < 16; ++t2) {
    const int och = t2 >> 2, kch = t2 & 3;
    unsigned short* const bb = (t2 & 1) ? B21 : B20;
    if (kch == 0) {
#pragma unroll
      for (int i = 0; i < 4; ++i)
#pragma unroll
        for (int j = 0; j < 2; ++j) acc2[i][j] = zero;
    }
    if (t2 < 15) asm volatile("s_waitcnt vmcnt(4)" ::: "memory");
    else         asm volatile("s_waitcnt vmcnt(0)" ::: "memory");
    __builtin_amdgcn_s_barrier();
    asm volatile("" ::: "memory");
#pragma unroll
    for (int ks = 0; ks < 2; ++ks) {
      const int kb2 = kch * 8 + ks * 4 + quad;
      s16x8 af[4], bf[2];
#pragma unroll
      for (int i = 0; i < 4; ++i)
        af[i] = *(const s16x8*)&Ps[(i * 16 + nl) * 256 + ((kb2 ^ (nl & 7)) << 3)];
#pragma unroll
      for (int j = 0; j < 2; ++j)
        bf[j] = *(const s16x8*)&bb[(wn * 32 + j * 16 + nl) * 64 +
                                   (((ks * 4 + quad) ^ (nl & 7)) * 8)];
      __builtin_amdgcn_s_setprio(1);
#pragma unroll
      for (int i = 0; i < 4; ++i) {
        acc2[i][0] = MFMA_BF16(af[i], bf[0], acc2[i][0]);
        acc2[i][1] = MFMA_BF16(af[i], bf[1], acc2[i][1]);
      }
      __builtin_amdgcn_s_setprio(0);
    }
    asm volatile("" ::: "memory");
    __builtin_amdgcn_s_barrier();
    if (kch == 3) {
#pragma unroll
      for (int i = 0; i < 4; ++i) {
        const int seq = w * 128 + half * 64 + i * 16 + quad * 4;
        float* dst = out + (size_t)(b * 8192 + seq) * 512;
#pragma unroll
        for (int j = 0; j < 2; ++j) {
          const int o = och * 128 + wn * 32 + j * 16 + nl;
#pragma unroll
          for (int r = 0; r < 4; ++r) dst[(size_t)r * 512 + o] = acc2[i][j][r] + bo[och][j];
        }
      }
    }
    if (t2 < 14) STAGE_B2(t2 + 2, bb);  // refill the buffer just consumed
  }
#undef STAGE_Q
#undef STAGE_K
#undef STAGE_B2
}

extern "C" void kernel_launch(void* const* d_in, const int* in_sizes, int n_in,
                              void* d_out, int out_size, void* d_ws, size_t ws_size,
                              hipStream_t stream) {
  const float* x = (const float*)d_in[0];
  const float* w_qkv = (const float*)d_in[1];
  const float* w_out = (const float*)d_in[2];
  const float* b_out = (const float*)d_in[3];
  float* out = (float*)d_out;

  char* ws = (char*)d_ws;
  // Layout (97.5 MB):
  //   Q   @  0  (32MB)
  //   K   @ 32M (32MB)
  //   KWT @ 64M (32MB)
  //   wb  @ 96M (1MB), wob @ 97M (0.5MB)
  unsigned short* Q = (unsigned short*)ws;
  unsigned short* K = (unsigned short*)(ws + (size_t)33554432);
  unsigned short* KWT = (unsigned short*)(ws + (size_t)67108864);
  unsigned short* wb = (unsigned short*)(ws + (size_t)100663296);
  unsigned short* wob = (unsigned short*)(ws + (size_t)100663296 + 1048576);

  cvt_w<<<dim3(384), dim3(256), 0, stream>>>(w_qkv, w_out, wb, wob);
  gemm_qk<<<dim3(2048), dim3(256), 0, stream>>>(x, wb, Q, K);
  gemm_kwt<<<dim3(1024), dim3(256), 0, stream>>>(K, wob, KWT);
  attn64<<<dim3(512), dim3(256), 0, stream>>>(Q, K, KWT, b_out, out);
}

// Round 7
// 239.789 us; speedup vs baseline: 1.0254x; 1.0254x over previous
//
#include <hip/hip_runtime.h>
#include <cstdint>
#include <cstddef>

typedef float f32x4 __attribute__((ext_vector_type(4)));
typedef short s16x8 __attribute__((ext_vector_type(8)));
typedef short s16x4 __attribute__((ext_vector_type(4)));

#define MFMA_BF16(a, b, c) __builtin_amdgcn_mfma_f32_16x16x32_bf16((a), (b), (c), 0, 0, 0)

// async global->LDS DMA, 16B/lane: lands at ldsbase + lane*16 (wave-uniform base)
#define GLD16(g, l)                                                            \
  __builtin_amdgcn_global_load_lds(                                            \
      (const __attribute__((address_space(1))) void*)(g),                      \
      (__attribute__((address_space(3))) void*)(l), 16, 0, 0)

__device__ __forceinline__ unsigned short f2bf(float f) {
  unsigned int u = __float_as_uint(f);
  u += 0x7FFFu + ((u >> 16) & 1u);
  return (unsigned short)(u >> 16);
}

__device__ __forceinline__ s16x8 cvt8(const float* __restrict__ src) {
  const float4 f0 = *(const float4*)src;
  const float4 f1 = *(const float4*)(src + 4);
  s16x8 h;
  h[0] = (short)f2bf(f0.x); h[1] = (short)f2bf(f0.y);
  h[2] = (short)f2bf(f0.z); h[3] = (short)f2bf(f0.w);
  h[4] = (short)f2bf(f1.x); h[5] = (short)f2bf(f1.y);
  h[6] = (short)f2bf(f1.z); h[7] = (short)f2bf(f1.w);
  return h;
}

// ---------------------------------------------------------------------------
// cvt_bf16 (R5 restored): x -> xb, w_qkv[0:1024] -> wb, w_out -> wob.
// R6's in-GEMM fusion duplicated the x conversion 8x (one per n-tile block)
// -> gemm_qk 81us. Separate one-shot pass is cheaper in total.
// ---------------------------------------------------------------------------
#define XN 16777216   // 4*8192*512
#define WQN 524288    // 1024*512
__global__ __launch_bounds__(256)
void cvt_bf16(const float* __restrict__ x, const float* __restrict__ wqkv,
              const float* __restrict__ wout, unsigned short* __restrict__ xb,
              unsigned short* __restrict__ wb, unsigned short* __restrict__ wob) {
  const size_t i = (size_t)(blockIdx.x * 256 + threadIdx.x) * 8;
  const float* src;
  unsigned short* dst;
  if (i < XN) { src = x + i; dst = xb + i; }
  else if (i < XN + WQN) { src = wqkv + (i - XN); dst = wb + (i - XN); }
  else { src = wout + (i - XN - WQN); dst = wob + (i - XN - WQN); }
  *(s16x8*)dst = cvt8(src);
}

// ---------------------------------------------------------------------------
// gemm_qk v2: [Q|K] = xb @ wb^T, M=32768 N=1024 K=512. R5 structure + T3/T4:
// double-buffered LDS, chunk s+1 prefetched before waiting on chunk s with
// COUNTED vmcnt(8) (8 older loads drain, 8 newer in flight), raw s_barrier
// (no __syncthreads: it drains vmcnt(0) and kills the pipeline) — the exact
// transformation that took attn64 84->56us in R3. SWAPPED staging: D
// transposed -> packed 8B Q/K stores. XCD-aware block map.
// ---------------------------------------------------------------------------
__global__ __launch_bounds__(256)
void gemm_qk(const unsigned short* __restrict__ xb, const unsigned short* __restrict__ wb,
             unsigned short* __restrict__ Q, unsigned short* __restrict__ K) {
  __shared__ unsigned short As[2][128 * 64];  // W tiles (dbuf)
  __shared__ unsigned short Bs[2][128 * 64];  // x tiles (dbuf)
  const int t = threadIdx.x, lane = t & 63, wid = t >> 6;
  const int wm = wid >> 1, wn = wid & 1;
  const int nl = lane & 15, quad = lane >> 4;
  const int sub = lane >> 3, lblk = (lane & 7) ^ sub;
  const int l = blockIdx.x;
  const int xcd = l & 7, g = l >> 3;
  const int mt = (g >> 3) * 8 + xcd, nt = g & 7;
  const int m0 = mt * 128, n0 = nt * 128;

  const f32x4 zero = {0.f, 0.f, 0.f, 0.f};
  f32x4 acc[4][4];
#pragma unroll
  for (int i = 0; i < 4; ++i)
#pragma unroll
    for (int j = 0; j < 4; ++j) acc[i][j] = zero;

  const unsigned short* gX = xb + (size_t)(m0 + wid * 32 + sub) * 512 + lblk * 8;
  const unsigned short* gW = wb + (size_t)(n0 + wid * 32 + sub) * 512 + lblk * 8;

#define STAGE_QK(kcc, p)                                                       \
  do {                                                                         \
    _Pragma("unroll") for (int ii = 0; ii < 4; ++ii)                           \
        GLD16(gW + (kcc) + (size_t)(ii * 8) * 512,                             \
              &As[p][(wid * 32 + ii * 8) * 64]);                               \
    _Pragma("unroll") for (int ii = 0; ii < 4; ++ii)                           \
        GLD16(gX + (kcc) + (size_t)(ii * 8) * 512,                             \
              &Bs[p][(wid * 32 + ii * 8) * 64]);                               \
  } while (0)

  STAGE_QK(0, 0);
  for (int s = 0; s < 8; ++s) {
    const int p = s & 1;
    if (s < 7) {
      STAGE_QK((s + 1) * 64, p ^ 1);
      asm volatile("s_waitcnt vmcnt(8)" ::: "memory");  // chunk s ready, s+1 in flight
    } else {
      asm volatile("s_waitcnt vmcnt(0)" ::: "memory");
    }
    __builtin_amdgcn_s_barrier();
    asm volatile("" ::: "memory");
    const unsigned short* const asp = As[p];
    const unsigned short* const bsp = Bs[p];
#pragma unroll
    for (int ks = 0; ks < 2; ++ks) {
      s16x8 af[4], bf[4];
#pragma unroll
      for (int i = 0; i < 4; ++i)
        af[i] = *(const s16x8*)&asp[(wm * 64 + i * 16 + nl) * 64 +
                                    (((ks * 4 + quad) ^ (nl & 7)) * 8)];
#pragma unroll
      for (int j = 0; j < 4; ++j)
        bf[j] = *(const s16x8*)&bsp[(wn * 64 + j * 16 + nl) * 64 +
                                    (((ks * 4 + quad) ^ (nl & 7)) * 8)];
      __builtin_amdgcn_s_setprio(1);
#pragma unroll
      for (int i = 0; i < 4; ++i)
#pragma unroll
        for (int j = 0; j < 4; ++j) acc[i][j] = MFMA_BF16(af[i], bf[j], acc[i][j]);
      __builtin_amdgcn_s_setprio(0);
    }
    asm volatile("" ::: "memory");
    __builtin_amdgcn_s_barrier();
  }
#undef STAGE_QK
  // D rows = W-feature n (contiguous in reg r), cols = seq m -> packed stores
#pragma unroll
  for (int i = 0; i < 4; ++i) {
    const int n = n0 + wm * 64 + i * 16 + quad * 4;
    unsigned short* base = (n < 512 ? Q : K);
    const int nn = n & 511;
#pragma unroll
    for (int j = 0; j < 4; ++j) {
      const int m = m0 + wn * 64 + j * 16 + nl;
      s16x4 h;
#pragma unroll
      for (int r = 0; r < 4; ++r) h[r] = (short)f2bf(acc[i][j][r]);
      *(s16x4*)&base[(size_t)m * 512 + nn] = h;
    }
  }
}

// ---------------------------------------------------------------------------
// gemm_kwt v2: KWT[b][o][seq] = (K @ wob^T)^T, same T3/T4 dbuf counted-vmcnt
// treatment as gemm_qk. Normal operand order -> packed 8B transposed stores.
// ---------------------------------------------------------------------------
__global__ __launch_bounds__(256)
void gemm_kwt(const unsigned short* __restrict__ K, const unsigned short* __restrict__ wob,
              unsigned short* __restrict__ KWT) {
  __shared__ unsigned short As[2][128 * 64];
  __shared__ unsigned short Bs[2][128 * 64];
  const int t = threadIdx.x, lane = t & 63, wid = t >> 6;
  const int wm = wid >> 1, wn = wid & 1;
  const int nl = lane & 15, quad = lane >> 4;
  const int sub = lane >> 3, lblk = (lane & 7) ^ sub;
  const int l = blockIdx.x;
  const int xcd = l & 7, g = l >> 3;
  const int mt = (g >> 2) * 8 + xcd, nt = g & 3;
  const int m0 = mt * 128, n0 = nt * 128;

  const f32x4 zero = {0.f, 0.f, 0.f, 0.f};
  f32x4 acc[4][4];
#pragma unroll
  for (int i = 0; i < 4; ++i)
#pragma unroll
    for (int j = 0; j < 4; ++j) acc[i][j] = zero;

  const unsigned short* gA = K + (size_t)(m0 + wid * 32 + sub) * 512 + lblk * 8;
  const unsigned short* gB = wob + (size_t)(n0 + wid * 32 + sub) * 512 + lblk * 8;

#define STAGE_KW(kcc, p)                                                       \
  do {                                                                         \
    _Pragma("unroll") for (int ii = 0; ii < 4; ++ii)                           \
        GLD16(gA + (kcc) + (size_t)(ii * 8) * 512,                             \
              &As[p][(wid * 32 + ii * 8) * 64]);                               \
    _Pragma("unroll") for (int ii = 0; ii < 4; ++ii)                           \
        GLD16(gB + (kcc) + (size_t)(ii * 8) * 512,                             \
              &Bs[p][(wid * 32 + ii * 8) * 64]);                               \
  } while (0)

  STAGE_KW(0, 0);
  for (int s = 0; s < 8; ++s) {
    const int p = s & 1;
    if (s < 7) {
      STAGE_KW((s + 1) * 64, p ^ 1);
      asm volatile("s_waitcnt vmcnt(8)" ::: "memory");
    } else {
      asm volatile("s_waitcnt vmcnt(0)" ::: "memory");
    }
    __builtin_amdgcn_s_barrier();
    asm volatile("" ::: "memory");
    const unsigned short* const asp = As[p];
    const unsigned short* const bsp = Bs[p];
#pragma unroll
    for (int ks = 0; ks < 2; ++ks) {
      s16x8 af[4], bf[4];
#pragma unroll
      for (int i = 0; i < 4; ++i)
        af[i] = *(const s16x8*)&asp[(wm * 64 + i * 16 + nl) * 64 +
                                    (((ks * 4 + quad) ^ (nl & 7)) * 8)];
#pragma unroll
      for (int j = 0; j < 4; ++j)
        bf[j] = *(const s16x8*)&bsp[(wn * 64 + j * 16 + nl) * 64 +
                                    (((ks * 4 + quad) ^ (nl & 7)) * 8)];
      __builtin_amdgcn_s_setprio(1);
#pragma unroll
      for (int i = 0; i < 4; ++i)
#pragma unroll
        for (int j = 0; j < 4; ++j) acc[i][j] = MFMA_BF16(af[i], bf[j], acc[i][j]);
      __builtin_amdgcn_s_setprio(0);
    }
    asm volatile("" ::: "memory");
    __builtin_amdgcn_s_barrier();
  }
#undef STAGE_KW
#pragma unroll
  for (int i = 0; i < 4; ++i) {
    const int ms = m0 + wm * 64 + i * 16 + quad * 4;
    const int b = ms >> 13, ns = ms & 8191;
#pragma unroll
    for (int j = 0; j < 4; ++j) {
      const int o = n0 + wn * 64 + j * 16 + nl;
      s16x4 h;
#pragma unroll
      for (int r = 0; r < 4; ++r) h[r] = (short)f2bf(acc[i][j][r]);
      *(s16x4*)&KWT[(size_t)(b * 512 + o) * 8192 + ns] = h;
    }
  }
}

// ---------------------------------------------------------------------------
// attn64 (R5 verbatim — best measured 56.6us): K dbuf + single-Q counted-
// vmcnt pipeline, 72KB LDS, phase 2 dbuf counted-vmcnt with barriers.
// ---------------------------------------------------------------------------
__global__ __launch_bounds__(256)
void attn64(const unsigned short* __restrict__ Q, const unsigned short* __restrict__ K,
            const unsigned short* __restrict__ KWT, const float* __restrict__ bias,
            float* __restrict__ out) {
  __shared__ __align__(16) char smem[73728];
  unsigned short* const Qb  = (unsigned short*)smem;             // 8KB  [0,8K)
  unsigned short* const Kbo = (unsigned short*)(smem + 8192);    // 32KB [8K,40K)  odd chunks
  unsigned short* const Kbe = (unsigned short*)(smem + 40960);   // 32KB [40K,72K) even chunks
  unsigned short* const Ps  = (unsigned short*)smem;             // 32KB [0,32K)   phase2
  float* const redm = (float*)(smem + 32768);                    // 1KB (dead Kbo top)
  float* const reds = (float*)(smem + 33792);                    // 1KB
  unsigned short* const B20 = (unsigned short*)(smem + 40960);   // 16KB alias Kbe
  unsigned short* const B21 = (unsigned short*)(smem + 57344);   // 16KB alias Kbe

  const int t = threadIdx.x, lane = t & 63, wid = t >> 6;
  const int wn = wid;  // 4 waves split the 256 sim cols
  const int nl = lane & 15, quad = lane >> 4;
  const int sub = lane >> 3, lblk = (lane & 7) ^ sub;
  // paired-XCD decode: bx = g*16 + half*8 + xcd
  const int bx = blockIdx.x;
  const int xcd = bx & 7, half = (bx >> 3) & 1, g = bx >> 4;
  const int wb = g * 8 + xcd, b = wb >> 6, w = wb & 63;

  const unsigned short* Qg = Q + (size_t)(b * 8192 + w * 128 + half * 64) * 512;
  const unsigned short* Kg = K + (size_t)(b * 8192) * 512;
  const unsigned short* KWTb = KWT + (size_t)(b * 512) * 8192;
  const int seqbase = w * 128 - 128;

#define STAGE_Q(kcc)                                                           \
  do {                                                                         \
    _Pragma("unroll") for (int ii = 0; ii < 2; ++ii)                           \
        GLD16(Qg + (size_t)(wid * 16 + ii * 8 + sub) * 512 + (kcc) + lblk * 8, \
              Qb + (wid * 16 + ii * 8) * 64);                                  \
  } while (0)

#define STAGE_K(kcc, kb)                                                       \
  do {                                                                         \
    _Pragma("unroll") for (int ii = 0; ii < 8; ++ii) {                         \
      int sq_ = seqbase + wid * 64 + ii * 8 + sub;                             \
      if (sq_ < 0) sq_ = 0;                                                    \
      GLD16(Kg + (size_t)sq_ * 512 + (kcc) + lblk * 8,                         \
            (kb) + (wid * 64 + ii * 8) * 64);                                  \
    }                                                                          \
  } while (0)

#define STAGE_B2(tt, bb)                                                       \
  do {                                                                         \
    const int och_ = (tt) >> 2, kch_ = (tt) & 3;                               \
    int sq_ = seqbase + kch_ * 64 + lblk * 8;                                  \
    if (sq_ < 0) sq_ = 0;                                                      \
    _Pragma("unroll") for (int ii = 0; ii < 4; ++ii)                           \
        GLD16(KWTb + (size_t)(och_ * 128 + wid * 32 + ii * 8 + sub) * 8192 + sq_, \
              (bb) + (wid * 32 + ii * 8) * 64);                                \
  } while (0)

  float bo[4][2];
#pragma unroll
  for (int och = 0; och < 4; ++och)
#pragma unroll
    for (int j = 0; j < 2; ++j) bo[och][j] = bias[och * 128 + wn * 32 + j * 16 + nl];

  const f32x4 zero = {0.f, 0.f, 0.f, 0.f};
  f32x4 acc[4][4];
#pragma unroll
  for (int i = 0; i < 4; ++i)
#pragma unroll
    for (int j = 0; j < 4; ++j) acc[i][j] = zero;

  // ---- phase 1: sim = Q.K2^T, K dbuf + single-Q counted-vmcnt pipeline ----
  STAGE_K(0, Kbe);
  STAGE_Q(0);
#pragma unroll
  for (int s = 0; s < 8; ++s) {
    unsigned short* const kb = (s & 1) ? Kbo : Kbe;
    if (s < 7) {
      STAGE_K((s + 1) * 64, (s & 1) ? Kbe : Kbo);
      asm volatile("s_waitcnt vmcnt(8)" ::: "memory");  // K(s),Q(s) ready; K(s+1) in flight
    } else {
      STAGE_B2(0, B20);  // Kbe dead after s=6 -> phase-2 prefetch begins
      asm volatile("s_waitcnt vmcnt(4)" ::: "memory");
    }
    __builtin_amdgcn_s_barrier();
    asm volatile("" ::: "memory");
#pragma unroll
    for (int ks = 0; ks < 2; ++ks) {
      s16x8 af[4], bf[4];
#pragma unroll
      for (int i = 0; i < 4; ++i)
        af[i] = *(const s16x8*)&Qb[(i * 16 + nl) * 64 +
                                   (((ks * 4 + quad) ^ (nl & 7)) * 8)];
#pragma unroll
      for (int j = 0; j < 4; ++j)
        bf[j] = *(const s16x8*)&kb[(wn * 64 + j * 16 + nl) * 64 +
                                   (((ks * 4 + quad) ^ (nl & 7)) * 8)];
      __builtin_amdgcn_s_setprio(1);
#pragma unroll
      for (int i = 0; i < 4; ++i)
#pragma unroll
        for (int j = 0; j < 4; ++j) acc[i][j] = MFMA_BF16(af[i], bf[j], acc[i][j]);
      __builtin_amdgcn_s_setprio(0);
    }
    asm volatile("" ::: "memory");
    __builtin_amdgcn_s_barrier();
    if (s < 7) STAGE_Q((s + 1) * 64);  // Qb reads of step s done (barrier above)
  }
  STAGE_B2(1, B21);  // second phase-2 chunk rides under softmax

  // ---- softmax (raw barriers; no vmcnt drains) ----
  const float scale = 0.04419417382415922f;  // 512^-0.5
  float rmax[4][4];
#pragma unroll
  for (int i = 0; i < 4; ++i) {
#pragma unroll
    for (int r = 0; r < 4; ++r) {
      const int qrow = half * 64 + i * 16 + quad * 4 + r;  // within-window row
      float mx = -3.4e38f;
#pragma unroll
      for (int j = 0; j < 4; ++j) {
        const int col = wn * 64 + j * 16 + nl;
        float v = acc[i][j][r] * scale;
        if (col >= 128 && col - 128 > qrow) v = -3.0e38f;  // causal mask
        if (w == 0 && col < 128) v = 0.0f;                 // zero bucket: sim=0
        acc[i][j][r] = v;
        mx = fmaxf(mx, v);
      }
      rmax[i][r] = mx;
    }
  }
#pragma unroll
  for (int off = 1; off < 16; off <<= 1)
#pragma unroll
    for (int i = 0; i < 4; ++i)
#pragma unroll
      for (int r = 0; r < 4; ++r)
        rmax[i][r] = fmaxf(rmax[i][r], __shfl_xor(rmax[i][r], off, 64));
  if (nl == 0) {
#pragma unroll
    for (int i = 0; i < 4; ++i)
#pragma unroll
      for (int r = 0; r < 4; ++r)
        redm[(i * 16 + quad * 4 + r) * 4 + wn] = rmax[i][r];
  }
  asm volatile("s_waitcnt lgkmcnt(0)" ::: "memory");
  __builtin_amdgcn_s_barrier();
  asm volatile("" ::: "memory");
  float rsum[4][4];
#pragma unroll
  for (int i = 0; i < 4; ++i) {
#pragma unroll
    for (int r = 0; r < 4; ++r) {
      const f32x4 mv = *(const f32x4*)&redm[(i * 16 + quad * 4 + r) * 4];
      const float m = fmaxf(fmaxf(mv[0], mv[1]), fmaxf(mv[2], mv[3]));
      float s = 0.f;
#pragma unroll
      for (int j = 0; j < 4; ++j) {
        const float p = __expf(acc[i][j][r] - m);
        acc[i][j][r] = p;
        s += p;
      }
      rsum[i][r] = s;
    }
  }
#pragma unroll
  for (int off = 1; off < 16; off <<= 1)
#pragma unroll
    for (int i = 0; i < 4; ++i)
#pragma unroll
      for (int r = 0; r < 4; ++r) rsum[i][r] += __shfl_xor(rsum[i][r], off, 64);
  if (nl == 0) {
#pragma unroll
    for (int i = 0; i < 4; ++i)
#pragma unroll
      for (int r = 0; r < 4; ++r)
        reds[(i * 16 + quad * 4 + r) * 4 + wn] = rsum[i][r];
  }
  asm volatile("s_waitcnt lgkmcnt(0)" ::: "memory");
  __builtin_amdgcn_s_barrier();
  asm volatile("" ::: "memory");
  float invv[4][4];
#pragma unroll
  for (int i = 0; i < 4; ++i)
#pragma unroll
    for (int r = 0; r < 4; ++r) {
      const f32x4 sv = *(const f32x4*)&reds[(i * 16 + quad * 4 + r) * 4];
      invv[i][r] = 1.0f / (sv[0] + sv[1] + sv[2] + sv[3]);
    }
  asm volatile("s_waitcnt lgkmcnt(0)" ::: "memory");
  __builtin_amdgcn_s_barrier();
  asm volatile("" ::: "memory");
  // normalize, write P -> LDS (swizzled row-major 64x256 bf16)
#pragma unroll
  for (int i = 0; i < 4; ++i) {
#pragma unroll
    for (int r = 0; r < 4; ++r) {
      const int row = i * 16 + quad * 4 + r;
#pragma unroll
      for (int j = 0; j < 4; ++j) {
        const int col = wn * 64 + j * 16 + nl;
        float pv = acc[i][j][r] * invv[i][r];
        if (w == 0 && col < 128) pv = 0.0f;  // zero V bucket
        const int cb = col >> 3;
        Ps[row * 256 + (((cb ^ (row & 7)) << 3) | (col & 7))] = f2bf(pv);
      }
    }
  }
  asm volatile("s_waitcnt lgkmcnt(0)" ::: "memory");
  __builtin_amdgcn_s_barrier();
  asm volatile("" ::: "memory");

  // ---- phase 2: out = P @ KWT^T, dbuf counted-vmcnt ----
  f32x4 acc2[4][2];
#pragma unroll
  for (int t2 = 0; t2 < 16; ++t2) {
    const int och = t2 >> 2, kch = t2 & 3;
    unsigned short* const bb = (t2 & 1) ? B21 : B20;
    if (kch == 0) {
#pragma unroll
      for (int i = 0; i < 4; ++i)
#pragma unroll
        for (int j = 0; j < 2; ++j) acc2[i][j] = zero;
    }
    if (t2 < 15) asm volatile("s_waitcnt vmcnt(4)" ::: "memory");
    else         asm volatile("s_waitcnt vmcnt(0)" ::: "memory");
    __builtin_amdgcn_s_barrier();
    asm volatile("" ::: "memory");
#pragma unroll
    for (int ks = 0; ks < 2; ++ks) {
      const int kb2 = kch * 8 + ks * 4 + quad;
      s16x8 af[4], bf[2];
#pragma unroll
      for (int i = 0; i < 4; ++i)
        af[i] = *(const s16x8*)&Ps[(i * 16 + nl) * 256 + ((kb2 ^ (nl & 7)) << 3)];
#pragma unroll
      for (int j = 0; j < 2; ++j)
        bf[j] = *(const s16x8*)&bb[(wn * 32 + j * 16 + nl) * 64 +
                                   (((ks * 4 + quad) ^ (nl & 7)) * 8)];
      __builtin_amdgcn_s_setprio(1);
#pragma unroll
      for (int i = 0; i < 4; ++i) {
        acc2[i][0] = MFMA_BF16(af[i], bf[0], acc2[i][0]);
        acc2[i][1] = MFMA_BF16(af[i], bf[1], acc2[i][1]);
      }
      __builtin_amdgcn_s_setprio(0);
    }
    asm volatile("" ::: "memory");
    __builtin_amdgcn_s_barrier();
    if (kch == 3) {
#pragma unroll
      for (int i = 0; i < 4; ++i) {
        const int seq = w * 128 + half * 64 + i * 16 + quad * 4;
        float* dst = out + (size_t)(b * 8192 + seq) * 512;
#pragma unroll
        for (int j = 0; j < 2; ++j) {
          const int o = och * 128 + wn * 32 + j * 16 + nl;
#pragma unroll
          for (int r = 0; r < 4; ++r) dst[(size_t)r * 512 + o] = acc2[i][j][r] + bo[och][j];
        }
      }
    }
    if (t2 < 14) STAGE_B2(t2 + 2, bb);  // refill the buffer just consumed
  }
#undef STAGE_Q
#undef STAGE_K
#undef STAGE_B2
}

extern "C" void kernel_launch(void* const* d_in, const int* in_sizes, int n_in,
                              void* d_out, int out_size, void* d_ws, size_t ws_size,
                              hipStream_t stream) {
  const float* x = (const float*)d_in[0];
  const float* w_qkv = (const float*)d_in[1];
  const float* w_out = (const float*)d_in[2];
  const float* b_out = (const float*)d_in[3];
  float* out = (float*)d_out;

  char* ws = (char*)d_ws;
  // Layout (97.5 MB, within the 112 MB proven budget):
  //   Q   @  0  (32MB)
  //   K   @ 32M (32MB)
  //   xb  @ 64M (32MB)  dead after gemm_qk
  //   KWT @ 64M (32MB)  written by gemm_kwt (aliases xb)
  //   wb  @ 96M (1MB), wob @ 97M (0.5MB)
  unsigned short* Q = (unsigned short*)ws;
  unsigned short* K = (unsigned short*)(ws + (size_t)33554432);
  unsigned short* xb = (unsigned short*)(ws + (size_t)67108864);
  unsigned short* KWT = (unsigned short*)(ws + (size_t)67108864);
  unsigned short* wb = (unsigned short*)(ws + (size_t)100663296);
  unsigned short* wob = (unsigned short*)(ws + (size_t)100663296 + 1048576);

  cvt_bf16<<<dim3(8576), dim3(256), 0, stream>>>(x, w_qkv, w_out, xb, wb, wob);
  gemm_qk<<<dim3(2048), dim3(256), 0, stream>>>(xb, wb, Q, K);
  gemm_kwt<<<dim3(1024), dim3(256), 0, stream>>>(K, wob, KWT);
  attn64<<<dim3(512), dim3(256), 0, stream>>>(Q, K, KWT, b_out, out);
}